// Round 16
// baseline (3408.286 us; speedup 1.0000x reference)
//
#include <hip/hip_runtime.h>
#include <hip/hip_bf16.h>
#include <stdint.h>

#define S_LEN 2048
#define NQh   40
#define NKVh  8
#define HD    128
#define HIDd  5120
#define QKV_C 7208
#define QKV_P 7424   // padded to multiple of 256
#define NROW  (S_LEN * NQh)   // 81920 (q-row, head) pairs

typedef unsigned short u16;
typedef short bf16x8 __attribute__((ext_vector_type(8)));
typedef float f32x4  __attribute__((ext_vector_type(4)));
typedef u16   u16x4  __attribute__((ext_vector_type(4)));

typedef const __attribute__((address_space(1))) void* gas_ptr;
typedef __attribute__((address_space(3))) void*       las_ptr;

#define MFMA16(a, b, c) __builtin_amdgcn_mfma_f32_16x16x32_bf16(a, b, c, 0, 0, 0)

__device__ __forceinline__ u16 f2bf(float f) {
  union { float f; unsigned u; } v; v.f = f;
  return (u16)((v.u + 0x7fffu + ((v.u >> 16) & 1u)) >> 16);
}
__device__ __forceinline__ u16 f2bf_c(float f) {
  union { __hip_bfloat16 b; u16 u; } v;
  v.b = __float2bfloat16(f);
  return v.u;
}
__device__ __forceinline__ float b2f(u16 b) {
  union { unsigned u; float f; } v; v.u = ((unsigned)b) << 16; return v.f;
}

__device__ __forceinline__ float wave_sum64(float x) {
#pragma unroll
  for (int m = 32; m > 0; m >>= 1) x += __shfl_xor(x, m, 64);
  return x;
}

// C-store helpers (rows r at stride N, col fixed per lane)
__device__ __forceinline__ void cstore(float* cp, long strideN, const f32x4& v) {
#pragma unroll
  for (int r = 0; r < 4; ++r) cp[(long)r * strideN] = v[r];
}
__device__ __forceinline__ void cstore(u16* cp, long strideN, const f32x4& v) {
#pragma unroll
  for (int r = 0; r < 4; ++r) cp[(long)r * strideN] = f2bf_c(v[r]);
}

// ---------------- Kernel 1: pre-norm RMSNorm -> bf16 ----------------
__global__ __launch_bounds__(256) void prenorm_kernel(
    const float* __restrict__ x, const float* __restrict__ w, u16* __restrict__ xn) {
  int row = blockIdx.x;
  const float4* xr = (const float4*)(x + (size_t)row * HIDd);
  const float4* wr = (const float4*)w;
  float4 vx[5];
  float ss = 0.f;
#pragma unroll
  for (int c = 0; c < 5; ++c) {
    int i = c * 256 + threadIdx.x;
    vx[c] = xr[i];
    ss += vx[c].x * vx[c].x + vx[c].y * vx[c].y + vx[c].z * vx[c].z + vx[c].w * vx[c].w;
  }
  ss = wave_sum64(ss);
  __shared__ float red[4];
  if ((threadIdx.x & 63) == 0) red[threadIdx.x >> 6] = ss;
  __syncthreads();
  float tot = red[0] + red[1] + red[2] + red[3];
  float n = rsqrtf(tot * (1.f / HIDd) + 1e-6f);
  u16x4* out = (u16x4*)(xn + (size_t)row * HIDd);
#pragma unroll
  for (int c = 0; c < 5; ++c) {
    int i = c * 256 + threadIdx.x;
    float4 vw = wr[i];
    u16x4 o;
    o.x = f2bf(vx[c].x * n * vw.x);
    o.y = f2bf(vx[c].y * n * vw.y);
    o.z = f2bf(vx[c].z * n * vw.z);
    o.w = f2bf(vx[c].w * n * vw.w);
    out[i] = o;
  }
}

// ---------------- Kernel 2: transpose + fp32->bf16 (vectorized) ----------------
__global__ __launch_bounds__(256) void transpose_cvt(
    const float* __restrict__ src, u16* __restrict__ dst,
    int C, long ld_src, long ld_dst, long srcZ, long dstZ) {
  src += (long)blockIdx.z * srcZ;
  dst += (long)blockIdx.z * dstZ;
  __shared__ float t[32][34];
  int c0 = blockIdx.x * 32, r0 = blockIdx.y * 32;
  {
    int lc = threadIdx.x & 15, lr = threadIdx.x >> 4;
#pragma unroll
    for (int i = 0; i < 32; i += 16) {
      int r = r0 + lr + i;
      int c = c0 + lc * 2;
      float2 v = make_float2(0.f, 0.f);
      if (c < C) v = *(const float2*)(src + (long)r * ld_src + c);
      *(float2*)&t[lr + i][lc * 2] = v;
    }
  }
  __syncthreads();
  {
    int cc = threadIdx.x >> 3;
    int rq = (threadIdx.x & 7) * 4;
    int c = c0 + cc;
    if (c < C) {
      u16x4 o;
#pragma unroll
      for (int rr = 0; rr < 4; ++rr) o[rr] = f2bf(t[rq + rr][cc]);
      *(u16x4*)(dst + (long)c * ld_dst + (r0 + rq)) = o;
    }
  }
}

// ---------------- Kernel 2b: bf16 -> bf16 transpose (for V extraction) ----------------
__global__ __launch_bounds__(256) void transpose_bf16(
    const u16* __restrict__ src, u16* __restrict__ dst,
    long ld_src, long ld_dst, long srcZ, long dstZ) {
  src += (long)blockIdx.z * srcZ;
  dst += (long)blockIdx.z * dstZ;
  __shared__ u16 t[32][34];
  int c0 = blockIdx.x * 32, r0 = blockIdx.y * 32;
  {
    int lc = threadIdx.x & 15, lr = threadIdx.x >> 4;
#pragma unroll
    for (int i = 0; i < 32; i += 16)
      *(unsigned*)&t[lr + i][lc * 2] =
          *(const unsigned*)(src + (long)(r0 + lr + i) * ld_src + c0 + lc * 2);
  }
  __syncthreads();
  {
    int cc = threadIdx.x >> 3;
    int rq = (threadIdx.x & 7) * 4;
    u16x4 o;
#pragma unroll
    for (int rr = 0; rr < 4; ++rr) o[rr] = t[rq + rr][cc];
    *(u16x4*)(dst + (long)(c0 + cc) * ld_dst + (r0 + rq)) = o;
  }
}

// ---------------- Kernel 3: 256x256 GEMM, dbuf + 2 blocks/CU ----------------
// 8 waves (2M x 4N). K split into NP = K/32 k-halves; 2-slot LDS double buffer
// (16KB A + 16KB B per slot = 64 KiB total) -> 2 blocks/CU co-resident
// (launch_bounds(512,4), VGPR cap 128). Per phase: RD(i) -> STG(i+1, other
// slot) -> 32 MFMA -> s_waitcnt vmcnt(0) lgkmcnt(0) -> barrier. The per-phase
// drain is covered by the co-resident block's waves (m114 overlap).
// Hazards: STG(i+1) overwrites slot of i-1, whose reads drained at phase i-1's
// merged wait; RD(i) sees slot i complete via phase i-1's vmcnt(0)+barrier.
// Row-local XOR swizzle ((byte>>7)&3)<<4 on stage source and ds_read offsets.
template<typename OutT>
__global__ __launch_bounds__(512, 4) void gemm8(
    const u16* __restrict__ A, const u16* __restrict__ BT, OutT* __restrict__ C,
    int M, int N, int K) {
  __shared__ __align__(16) char AL[2 * 16384];
  __shared__ __align__(16) char BL[2 * 16384];

  int tid = threadIdx.x, w = tid >> 6, l = tid & 63;
  int wm = w >> 2, wn = w & 3;
  int g = l >> 4, q = l & 15;

  int nwg = gridDim.x * gridDim.y;
  int wgid = blockIdx.y * gridDim.x + blockIdx.x;
  int cpx = nwg >> 3;
  int swz = (wgid & 7) * cpx + (wgid >> 3);
  int bx = swz % gridDim.x, by = swz / gridDim.x;
  long mBase = (long)by * 256, nBase = (long)bx * 256;
  long Kb = (long)K * 2;
  const char* Ag = (const char*)A + mBase * Kb;
  const char* Bg = (const char*)BT + nBase * Kb;

  int d0 = tid * 16, d1 = 8192 + tid * 16;
  long soff0 = (long)(d0 >> 6) * Kb + ((d0 & 63) ^ (((d0 >> 7) & 3) << 4));
  long soff1 = (long)(d1 >> 6) * Kb + ((d1 & 63) ^ (((d1 >> 7) & 3) << 4));

#define STG(J)                                                                  \
  do {                                                                          \
    long kb_ = (long)(J) * 64;                                                  \
    char* la_ = AL + ((J) & 1) * 16384;                                         \
    char* lb_ = BL + ((J) & 1) * 16384;                                         \
    __builtin_amdgcn_global_load_lds((gas_ptr)(Ag + soff0 + kb_),               \
        (las_ptr)(la_ + d0), 16, 0, 0);                                         \
    __builtin_amdgcn_global_load_lds((gas_ptr)(Ag + soff1 + kb_),               \
        (las_ptr)(la_ + d1), 16, 0, 0);                                         \
    __builtin_amdgcn_global_load_lds((gas_ptr)(Bg + soff0 + kb_),               \
        (las_ptr)(lb_ + d0), 16, 0, 0);                                         \
    __builtin_amdgcn_global_load_lds((gas_ptr)(Bg + soff1 + kb_),               \
        (las_ptr)(lb_ + d1), 16, 0, 0);                                         \
  } while (0)

#define DRAIN_BARR                                                              \
  do {                                                                          \
    asm volatile("s_waitcnt vmcnt(0) lgkmcnt(0)" ::: "memory");                 \
    __builtin_amdgcn_sched_barrier(0);                                          \
    __builtin_amdgcn_s_barrier();                                               \
    __builtin_amdgcn_sched_barrier(0);                                          \
  } while (0)

  int offA[8], offB[4];
#pragma unroll
  for (int i = 0; i < 8; ++i) {
    int r = wm * 128 + i * 16 + q;
    offA[i] = r * 64 + ((g * 16) ^ (((r >> 1) & 3) << 4));
  }
#pragma unroll
  for (int j = 0; j < 4; ++j) {
    int r = wn * 64 + j * 16 + q;
    offB[j] = r * 64 + ((g * 16) ^ (((r >> 1) & 3) << 4));
  }

#define RD(J, AF, BF)                                                           \
  do {                                                                          \
    const char* ab_ = AL + ((J) & 1) * 16384;                                   \
    const char* bb_ = BL + ((J) & 1) * 16384;                                   \
    _Pragma("unroll") for (int ii = 0; ii < 8; ++ii)                            \
      AF[ii] = *(const bf16x8*)(ab_ + offA[ii]);                                \
    _Pragma("unroll") for (int j = 0; j < 4; ++j)                               \
      BF[j] = *(const bf16x8*)(bb_ + offB[j]);                                  \
  } while (0)
#define MM(AF, BF)                                                              \
  do {                                                                          \
    __builtin_amdgcn_s_setprio(1);                                              \
    _Pragma("unroll") for (int ii = 0; ii < 8; ++ii)                            \
      _Pragma("unroll") for (int j = 0; j < 4; ++j)                             \
        acc[ii][j] = MFMA16(AF[ii], BF[j], acc[ii][j]);                         \
    __builtin_amdgcn_s_setprio(0);                                              \
  } while (0)

  f32x4 acc[8][4] = {};
  int NP = K >> 5;                      // number of k-halves (K=5120 -> 160)

  bf16x8 af[8], bf[4];

  // prologue: stage slot0, drain, barrier
  STG(0);
  DRAIN_BARR;

  for (int i = 0; i < NP; ++i) {
    RD(i, af, bf);
    if (i + 1 < NP) STG(i + 1);
    MM(af, bf);
    DRAIN_BARR;
  }
#undef STG
#undef RD
#undef MM
#undef DRAIN_BARR

#pragma unroll
  for (int i = 0; i < 8; ++i)
#pragma unroll
    for (int j = 0; j < 4; ++j) {
      long mrow = mBase + wm * 128 + i * 16 + g * 4;
      long ncol = nBase + wn * 64 + j * 16 + q;
      cstore(C + mrow * N + ncol, N, acc[i][j]);
    }
}

// ---------------- Kernel 4: split + head-RMSNorm + RoPE + gate (bf16 qkv) ----------------
__global__ __launch_bounds__(256) void split_kernel(
    const u16* __restrict__ qkv, const float* __restrict__ cosb,
    const float* __restrict__ sinb, const float* __restrict__ wq,
    const float* __restrict__ wk, u16* __restrict__ qb, u16* __restrict__ kb,
    float* __restrict__ gate) {
  int s = blockIdx.x;
  int w = threadIdx.x >> 6, l = threadIdx.x & 63;
  const u16* row = qkv + (size_t)s * QKV_P;
  float c0 = cosb[s * HD + l],      s0 = sinb[s * HD + l];
  float c1 = cosb[s * HD + 64 + l], s1 = sinb[s * HD + 64 + l];
  const float SCALE = 0.12751743f;  // (1/sqrt(128)) * log2(e)
  for (int h = w; h < NQh; h += 4) {
    float x0 = b2f(row[h * HD + l]), x1 = b2f(row[h * HD + 64 + l]);
    float ss = wave_sum64(x0 * x0 + x1 * x1);
    float n = rsqrtf(ss * (1.f / HD) + 1e-6f);
    x0 *= n * wq[l]; x1 *= n * wq[64 + l];
    qb[((size_t)s * NQh + h) * HD + l]      = f2bf((x0 * c0 - x1 * s0) * SCALE);
    qb[((size_t)s * NQh + h) * HD + 64 + l] = f2bf((x1 * c1 + x0 * s1) * SCALE);
  }
  for (int h = w; h < NKVh; h += 4) {
    float x0 = b2f(row[NQh * HD + h * HD + l]), x1 = b2f(row[NQh * HD + h * HD + 64 + l]);
    float ss = wave_sum64(x0 * x0 + x1 * x1);
    float n = rsqrtf(ss * (1.f / HD) + 1e-6f);
    x0 *= n * wk[l]; x1 *= n * wk[64 + l];
    kb[((size_t)h * S_LEN + s) * HD + l]      = f2bf(x0 * c0 - x1 * s0);
    kb[((size_t)h * S_LEN + s) * HD + 64 + l] = f2bf(x1 * c1 + x0 * s1);
  }
  if (threadIdx.x < NQh) {
    float gx = b2f(row[(NQh + 2 * NKVh) * HD + threadIdx.x]);
    gate[(size_t)s * NQh + threadIdx.x] = 1.f / (1.f + expf(-gx));
  }
}

// ---------------- Kernel 5: flash attention v8 (unchanged, passing) ----------------
__global__ __launch_bounds__(256) void attn_kernel(
    const u16* __restrict__ qb, const u16* __restrict__ kb,
    const u16* __restrict__ vT,
    u16* __restrict__ opart, float* __restrict__ lpart) {
  int L = blockIdx.x;                 // 0..1279
  int xcd = L & 7, t0 = L >> 3;       // t0: 0..159
  int G = xcd * 10 + (t0 >> 4);       // (head, z) group, 0..79
  int bx = t0 & 15;                   // s-chunk within group
  int h = G % NQh, z = G / NQh;
  int hk = h / 5;
  int w = threadIdx.x >> 6, l = threadIdx.x & 63;
  int g = l >> 4, q = l & 15;
  int s0 = bx * 128 + w * 32;
  int tid = threadIdx.x;

  __shared__ __align__(16) u16 Ks[2][32 * 128];     // 8KB x2 (swizzled content)
  __shared__ __align__(16) u16 Vs[2][128 * 32];     // 8KB x2 (swizzled content)
  __shared__ __align__(16) u16 Plds[4][2][16][40];  // per-wave private

  bf16x8 ones;
#pragma unroll
  for (int j = 0; j < 8; ++j) ones[j] = (short)0x3F80;  // bf16 1.0

  bf16x8 qf[2][4];
#pragma unroll
  for (int p = 0; p < 2; ++p)
#pragma unroll
    for (int kk = 0; kk < 4; ++kk)
      qf[p][kk] = *(const bf16x8*)(qb + ((size_t)(s0 + p * 16 + q) * NQh + h) * HD + kk * 32 + g * 8);

  const char* KhB = (const char*)(kb + ((size_t)hk * S_LEN + z * 1024) * HD);  // rows 256B
  const char* VhB = (const char*)(vT + (size_t)hk * HD * S_LEN + z * 1024);    // rows 4096B

  int Dk0 = tid * 16, Dk1 = 4096 + tid * 16;
  long ks0 = (long)(Dk0 >> 8) * 256 + ((Dk0 & 255) ^ (((Dk0 >> 8) & 7) << 4));
  long ks1 = (long)(Dk1 >> 8) * 256 + ((Dk1 & 255) ^ (((Dk1 >> 8) & 7) << 4));
  long vs0 = (long)(Dk0 >> 6) * 4096 + ((Dk0 & 63) ^ (((Dk0 >> 7) & 3) << 4));
  long vs1 = (long)(Dk1 >> 6) * 4096 + ((Dk1 & 63) ^ (((Dk1 >> 7) & 3) << 4));

#define STG(BUF, T_)                                                            \
  do {                                                                          \
    __builtin_amdgcn_global_load_lds((gas_ptr)(KhB + (long)(T_) * 8192 + ks0),  \
        (las_ptr)((char*)&Ks[BUF][0] + Dk0), 16, 0, 0);                         \
    __builtin_amdgcn_global_load_lds((gas_ptr)(KhB + (long)(T_) * 8192 + ks1),  \
        (las_ptr)((char*)&Ks[BUF][0] + Dk1), 16, 0, 0);                         \
    __builtin_amdgcn_global_load_lds((gas_ptr)(VhB + (long)(T_) * 64 + vs0),    \
        (las_ptr)((char*)&Vs[BUF][0] + Dk0), 16, 0, 0);                         \
    __builtin_amdgcn_global_load_lds((gas_ptr)(VhB + (long)(T_) * 64 + vs1),    \
        (las_ptr)((char*)&Vs[BUF][0] + Dk1), 16, 0, 0);                         \
  } while (0)

#define BARR                                                                    \
  do {                                                                          \
    __builtin_amdgcn_sched_barrier(0);                                          \
    __builtin_amdgcn_s_barrier();                                               \
    __builtin_amdgcn_sched_barrier(0);                                          \
  } while (0)

  f32x4 oacc[8][2] = {};
  f32x4 lacc[2] = {};
  int xq = (q & 7) << 4;              // K read swizzle (row = kt*16+q)
  int xv = ((q >> 1) & 3) << 4;       // V read swizzle (row = dt*16+q)

  STG(0, 0); STG(1, 1);
  __builtin_amdgcn_sched_barrier(0);
  asm volatile("s_waitcnt vmcnt(4)" ::: "memory");   // tile0 done
  BARR;

  for (int step = 0; step < 32; ++step) {
    const char* kc = (const char*)&Ks[step & 1][0];
    const char* vc = (const char*)&Vs[step & 1][0];

    f32x4 sacc[2][2] = {};
#pragma unroll
    for (int kk = 0; kk < 4; ++kk) {
#pragma unroll
      for (int kt = 0; kt < 2; ++kt) {
        bf16x8 kf = *(const bf16x8*)(kc + (kt * 16 + q) * 256 + ((kk * 64 + g * 16) ^ xq));
        sacc[kt][0] = MFMA16(kf, qf[0][kk], sacc[kt][0]);
        sacc[kt][1] = MFMA16(kf, qf[1][kk], sacc[kt][1]);
      }
    }
    bf16x8 va[8];
#pragma unroll
    for (int dt = 0; dt < 8; ++dt)
      va[dt] = *(const bf16x8*)(vc + (dt * 16 + q) * 64 + ((g * 16) ^ xv));

#pragma unroll
    for (int p = 0; p < 2; ++p) {
#pragma unroll
      for (int kt = 0; kt < 2; ++kt) {
        u16x4 pk;
#pragma unroll
        for (int r = 0; r < 4; ++r) pk[r] = f2bf_c(exp2f(sacc[kt][p][r]));
        *(u16x4*)&Plds[w][p][q][kt * 16 + g * 4] = pk;
      }
    }
    bf16x8 pf0 = *(const bf16x8*)&Plds[w][0][q][g * 8];
    bf16x8 pf1 = *(const bf16x8*)&Plds[w][1][q][g * 8];
    __builtin_amdgcn_s_setprio(1);
#pragma unroll
    for (int dt = 0; dt < 8; ++dt) {
      oacc[dt][0] = MFMA16(va[dt], pf0, oacc[dt][0]);
      oacc[dt][1] = MFMA16(va[dt], pf1, oacc[dt][1]);
    }
    lacc[0] = MFMA16(ones, pf0, lacc[0]);   // l += P . 1
    lacc[1] = MFMA16(ones, pf1, lacc[1]);
    __builtin_amdgcn_s_setprio(0);

    BARR;                               // all waves done reading buf(step)
    if (step + 2 < 32) {
      STG(step & 1, step + 2);
      __builtin_amdgcn_sched_barrier(0);
      asm volatile("s_waitcnt vmcnt(4)" ::: "memory");  // tile step+1 resident
      __builtin_amdgcn_sched_barrier(0);
    } else if (step + 1 < 32) {
      __builtin_amdgcn_sched_barrier(0);
      asm volatile("s_waitcnt vmcnt(0)" ::: "memory");
      __builtin_amdgcn_sched_barrier(0);
    }
    BARR;
  }
#undef STG
#undef BARR

#pragma unroll
  for (int p = 0; p < 2; ++p) {
    size_t row = (size_t)(s0 + p * 16 + q) * NQh + h;
    if (g == 0) lpart[(size_t)z * NROW + row] = lacc[p][0];
    u16* op = opart + ((size_t)z * NROW + row) * HD;
#pragma unroll
    for (int dt = 0; dt < 8; ++dt) {
      u16x4 o;
#pragma unroll
      for (int r = 0; r < 4; ++r) o[r] = f2bf_c(oacc[dt][p][r]);
      *(u16x4*)(op + dt * 16 + g * 4) = o;
    }
  }
}

// ---------------- Kernel 6: combine kv-split partials + gate ----------------
__global__ __launch_bounds__(256) void combine_kernel(
    const u16* __restrict__ opart, const float* __restrict__ lpart,
    const float* __restrict__ gate, u16* __restrict__ ob) {
  int t = blockIdx.x * 256 + threadIdx.x;
  int row = t >> 5, dv = (t & 31) * 4;
  float l0 = lpart[row], l1 = lpart[NROW + row];
  float sc = gate[row] / (l0 + l1);
  u16x4 o0 = *(const u16x4*)(opart + (size_t)row * HD + dv);
  u16x4 o1 = *(const u16x4*)(opart + (size_t)NROW * HD + (size_t)row * HD + dv);
  u16x4 o;
#pragma unroll
  for (int r = 0; r < 4; ++r) o[r] = f2bf(sc * (b2f(o0[r]) + b2f(o1[r])));
  *(u16x4*)(ob + (size_t)row * HD + dv) = o;
}

// ---------------- host ----------------
extern "C" void kernel_launch(void* const* d_in, const int* in_sizes, int n_in,
                              void* d_out, int out_size, void* d_ws, size_t ws_size,
                              hipStream_t stream) {
  const float* x     = (const float*)d_in[0];
  const float* rc    = (const float*)d_in[1];
  const float* rs    = (const float*)d_in[2];
  const float* wpre  = (const float*)d_in[3];
  const float* wqkv  = (const float*)d_in[4];
  const float* wqn   = (const float*)d_in[5];
  const float* wkn   = (const float*)d_in[6];
  const float* wproj = (const float*)d_in[7];
  float* out = (float*)d_out;

  char* ws = (char*)d_ws;
  size_t off = 0;
  auto alloc = [&](size_t bytes) -> void* {
    void* p = ws + off;
    off += (bytes + 255) & ~(size_t)255;
    return p;
  };
  u16*   xn     = (u16*)  alloc((size_t)S_LEN * HIDd * 2);        // dead after QKV GEMM
  u16*   wqkvT  = (u16*)  alloc((size_t)QKV_P * HIDd * 2);        // dead after QKV GEMM
  u16*   wprojT = (u16*)  alloc((size_t)HIDd * HIDd * 2);
  u16*   qkvb   = (u16*)  alloc((size_t)S_LEN * QKV_P * 2);       // bf16 qkv
  u16*   qb     = (u16*)  alloc((size_t)S_LEN * NQh * HD * 2);
  u16*   kb     = (u16*)  alloc((size_t)NKVh * S_LEN * HD * 2);
  u16*   vT     = (u16*)  alloc((size_t)NKVh * HD * S_LEN * 2);
  float* gate   = (float*)alloc((size_t)S_LEN * NQh * 4);
  u16*   ob     = (u16*)  alloc((size_t)S_LEN * NQh * HD * 2);
  if (off > ws_size) return;

  // attn partials overlap the dead xn+wqkvT region (~42.7MB < 97MB).
  u16*   opart = (u16*)ws;                                     // 2*NROW*HD bf16 = 42MB
  float* lpart = (float*)(opart + (size_t)2 * NROW * HD);      // 2*NROW f32

  prenorm_kernel<<<S_LEN, 256, 0, stream>>>(x, wpre, xn);
  transpose_cvt<<<dim3(QKV_P / 32, HIDd / 32, 1), 256, 0, stream>>>(
      wqkv, wqkvT, QKV_C, (long)QKV_C, (long)HIDd, 0, 0);
  transpose_cvt<<<dim3(HIDd / 32, HIDd / 32, 1), 256, 0, stream>>>(
      wproj, wprojT, HIDd, (long)HIDd, (long)HIDd, 0, 0);
  gemm8<u16><<<dim3(QKV_P / 256, S_LEN / 256), 512, 0, stream>>>(
      xn, wqkvT, qkvb, S_LEN, QKV_P, HIDd);
  split_kernel<<<S_LEN, 256, 0, stream>>>(qkvb, rc, rs, wqn, wkn, qb, kb, gate);
  transpose_bf16<<<dim3(HD / 32, S_LEN / 32, NKVh), 256, 0, stream>>>(
      qkvb + (NQh + NKVh) * HD, vT, (long)QKV_P, (long)S_LEN,
      128, (long)HD * S_LEN);
  attn_kernel<<<1280, 256, 0, stream>>>(qb, kb, vT, opart, lpart);
  combine_kernel<<<NROW * 32 / 256, 256, 0, stream>>>(
      opart, lpart, gate, ob);
  gemm8<float><<<dim3(HIDd / 256, S_LEN / 256), 512, 0, stream>>>(
      ob, wprojT, out, S_LEN, HIDd, HIDd);
}

// Round 17
// 570.822 us; speedup vs baseline: 5.9708x; 5.9708x over previous
//
#include <hip/hip_runtime.h>
#include <hip/hip_bf16.h>
#include <stdint.h>

#define S_LEN 2048
#define NQh   40
#define NKVh  8
#define HD    128
#define HIDd  5120
#define QKV_C 7208
#define QKV_P 7424   // padded to multiple of 256
#define NROW  (S_LEN * NQh)   // 81920 (q-row, head) pairs

typedef unsigned short u16;
typedef short bf16x8 __attribute__((ext_vector_type(8)));
typedef float f32x4  __attribute__((ext_vector_type(4)));
typedef u16   u16x4  __attribute__((ext_vector_type(4)));

typedef const __attribute__((address_space(1))) void* gas_ptr;
typedef __attribute__((address_space(3))) void*       las_ptr;

#define MFMA16(a, b, c) __builtin_amdgcn_mfma_f32_16x16x32_bf16(a, b, c, 0, 0, 0)

__device__ __forceinline__ u16 f2bf(float f) {
  union { float f; unsigned u; } v; v.f = f;
  return (u16)((v.u + 0x7fffu + ((v.u >> 16) & 1u)) >> 16);
}
__device__ __forceinline__ u16 f2bf_c(float f) {
  union { __hip_bfloat16 b; u16 u; } v;
  v.b = __float2bfloat16(f);
  return v.u;
}
__device__ __forceinline__ float b2f(u16 b) {
  union { unsigned u; float f; } v; v.u = ((unsigned)b) << 16; return v.f;
}

__device__ __forceinline__ float wave_sum64(float x) {
#pragma unroll
  for (int m = 32; m > 0; m >>= 1) x += __shfl_xor(x, m, 64);
  return x;
}

// C-store helpers (rows r at stride N, col fixed per lane)
__device__ __forceinline__ void cstore(float* cp, long strideN, const f32x4& v) {
#pragma unroll
  for (int r = 0; r < 4; ++r) cp[(long)r * strideN] = v[r];
}
__device__ __forceinline__ void cstore(u16* cp, long strideN, const f32x4& v) {
#pragma unroll
  for (int r = 0; r < 4; ++r) cp[(long)r * strideN] = f2bf_c(v[r]);
}

// ---------------- Kernel 1: pre-norm RMSNorm -> bf16 ----------------
__global__ __launch_bounds__(256) void prenorm_kernel(
    const float* __restrict__ x, const float* __restrict__ w, u16* __restrict__ xn) {
  int row = blockIdx.x;
  const float4* xr = (const float4*)(x + (size_t)row * HIDd);
  const float4* wr = (const float4*)w;
  float4 vx[5];
  float ss = 0.f;
#pragma unroll
  for (int c = 0; c < 5; ++c) {
    int i = c * 256 + threadIdx.x;
    vx[c] = xr[i];
    ss += vx[c].x * vx[c].x + vx[c].y * vx[c].y + vx[c].z * vx[c].z + vx[c].w * vx[c].w;
  }
  ss = wave_sum64(ss);
  __shared__ float red[4];
  if ((threadIdx.x & 63) == 0) red[threadIdx.x >> 6] = ss;
  __syncthreads();
  float tot = red[0] + red[1] + red[2] + red[3];
  float n = rsqrtf(tot * (1.f / HIDd) + 1e-6f);
  u16x4* out = (u16x4*)(xn + (size_t)row * HIDd);
#pragma unroll
  for (int c = 0; c < 5; ++c) {
    int i = c * 256 + threadIdx.x;
    float4 vw = wr[i];
    u16x4 o;
    o.x = f2bf(vx[c].x * n * vw.x);
    o.y = f2bf(vx[c].y * n * vw.y);
    o.z = f2bf(vx[c].z * n * vw.z);
    o.w = f2bf(vx[c].w * n * vw.w);
    out[i] = o;
  }
}

// ---------------- Kernel 2: transpose + fp32->bf16 (vectorized) ----------------
__global__ __launch_bounds__(256) void transpose_cvt(
    const float* __restrict__ src, u16* __restrict__ dst,
    int C, long ld_src, long ld_dst, long srcZ, long dstZ) {
  src += (long)blockIdx.z * srcZ;
  dst += (long)blockIdx.z * dstZ;
  __shared__ float t[32][34];
  int c0 = blockIdx.x * 32, r0 = blockIdx.y * 32;
  {
    int lc = threadIdx.x & 15, lr = threadIdx.x >> 4;
#pragma unroll
    for (int i = 0; i < 32; i += 16) {
      int r = r0 + lr + i;
      int c = c0 + lc * 2;
      float2 v = make_float2(0.f, 0.f);
      if (c < C) v = *(const float2*)(src + (long)r * ld_src + c);
      *(float2*)&t[lr + i][lc * 2] = v;
    }
  }
  __syncthreads();
  {
    int cc = threadIdx.x >> 3;
    int rq = (threadIdx.x & 7) * 4;
    int c = c0 + cc;
    if (c < C) {
      u16x4 o;
#pragma unroll
      for (int rr = 0; rr < 4; ++rr) o[rr] = f2bf(t[rq + rr][cc]);
      *(u16x4*)(dst + (long)c * ld_dst + (r0 + rq)) = o;
    }
  }
}

// ---------------- Kernel 2b: bf16 -> bf16 transpose (for V extraction) ----------------
__global__ __launch_bounds__(256) void transpose_bf16(
    const u16* __restrict__ src, u16* __restrict__ dst,
    long ld_src, long ld_dst, long srcZ, long dstZ) {
  src += (long)blockIdx.z * srcZ;
  dst += (long)blockIdx.z * dstZ;
  __shared__ u16 t[32][34];
  int c0 = blockIdx.x * 32, r0 = blockIdx.y * 32;
  {
    int lc = threadIdx.x & 15, lr = threadIdx.x >> 4;
#pragma unroll
    for (int i = 0; i < 32; i += 16)
      *(unsigned*)&t[lr + i][lc * 2] =
          *(const unsigned*)(src + (long)(r0 + lr + i) * ld_src + c0 + lc * 2);
  }
  __syncthreads();
  {
    int cc = threadIdx.x >> 3;
    int rq = (threadIdx.x & 7) * 4;
    u16x4 o;
#pragma unroll
    for (int rr = 0; rr < 4; ++rr) o[rr] = t[rq + rr][cc];
    *(u16x4*)(dst + (long)(c0 + cc) * ld_dst + (r0 + rq)) = o;
  }
}

// ---------------- Kernel 3: 256x256 GEMM, register-pipelined k-half ring ----------------
// (round-15 verified version: 175-177 us/dispatch, VGPR 124, 0 bank conflicts)
// 8 waves (2M x 4N). K split into NP = K/32 k-halves G(j); LDS ring of 4 halves
// (slot j&3, 16KB each for A and B = 128 KiB total).
// Invariant at phase i: G(i),G(i+1) resident; G(i+2),G(i+3) in flight.
// Phase i: RD G(i+1) -> alternate reg set | STG G(i+4) | MFMA current set |
//          vmcnt(8) completes G(i+2) | lgkmcnt(0) WAR guard | barrier.
// Tails: VMW(4) at i=NP-4, VMW(0) at i=NP-3.
// Row-local XOR swizzle ((byte>>7)&3)<<4 on stage source and ds_read offsets.
template<typename OutT>
__global__ __launch_bounds__(512, 1) void gemm8(
    const u16* __restrict__ A, const u16* __restrict__ BT, OutT* __restrict__ C,
    int M, int N, int K) {
  __shared__ __align__(16) char AL[4 * 16384];
  __shared__ __align__(16) char BL[4 * 16384];

  int tid = threadIdx.x, w = tid >> 6, l = tid & 63;
  int wm = w >> 2, wn = w & 3;
  int g = l >> 4, q = l & 15;

  int nwg = gridDim.x * gridDim.y;
  int wgid = blockIdx.y * gridDim.x + blockIdx.x;
  int cpx = nwg >> 3;
  int swz = (wgid & 7) * cpx + (wgid >> 3);
  int bx = swz % gridDim.x, by = swz / gridDim.x;
  long mBase = (long)by * 256, nBase = (long)bx * 256;
  long Kb = (long)K * 2;
  const char* Ag = (const char*)A + mBase * Kb;
  const char* Bg = (const char*)BT + nBase * Kb;

  int d0 = tid * 16, d1 = 8192 + tid * 16;
  long soff0 = (long)(d0 >> 6) * Kb + ((d0 & 63) ^ (((d0 >> 7) & 3) << 4));
  long soff1 = (long)(d1 >> 6) * Kb + ((d1 & 63) ^ (((d1 >> 7) & 3) << 4));

#define STG(J)                                                                  \
  do {                                                                          \
    long kb_ = (long)(J) * 64;                                                  \
    char* la_ = AL + ((J) & 3) * 16384;                                         \
    char* lb_ = BL + ((J) & 3) * 16384;                                         \
    __builtin_amdgcn_global_load_lds((gas_ptr)(Ag + soff0 + kb_),               \
        (las_ptr)(la_ + d0), 16, 0, 0);                                         \
    __builtin_amdgcn_global_load_lds((gas_ptr)(Ag + soff1 + kb_),               \
        (las_ptr)(la_ + d1), 16, 0, 0);                                         \
    __builtin_amdgcn_global_load_lds((gas_ptr)(Bg + soff0 + kb_),               \
        (las_ptr)(lb_ + d0), 16, 0, 0);                                         \
    __builtin_amdgcn_global_load_lds((gas_ptr)(Bg + soff1 + kb_),               \
        (las_ptr)(lb_ + d1), 16, 0, 0);                                         \
  } while (0)

#define VMW(NLIT)                                                               \
  do {                                                                          \
    asm volatile("s_waitcnt vmcnt(" #NLIT ")" ::: "memory");                    \
    __builtin_amdgcn_sched_barrier(0);                                          \
  } while (0)
#define LKW_BARR                                                                \
  do {                                                                          \
    asm volatile("s_waitcnt lgkmcnt(0)" ::: "memory");                          \
    __builtin_amdgcn_sched_barrier(0);                                          \
    __builtin_amdgcn_s_barrier();                                               \
    __builtin_amdgcn_sched_barrier(0);                                          \
  } while (0)

  int offA[8], offB[4];
#pragma unroll
  for (int i = 0; i < 8; ++i) {
    int r = wm * 128 + i * 16 + q;
    offA[i] = r * 64 + ((g * 16) ^ (((r >> 1) & 3) << 4));
  }
#pragma unroll
  for (int j = 0; j < 4; ++j) {
    int r = wn * 64 + j * 16 + q;
    offB[j] = r * 64 + ((g * 16) ^ (((r >> 1) & 3) << 4));
  }

#define RD(J, AF, BF)                                                           \
  do {                                                                          \
    const char* ab_ = AL + ((J) & 3) * 16384;                                   \
    const char* bb_ = BL + ((J) & 3) * 16384;                                   \
    _Pragma("unroll") for (int ii = 0; ii < 8; ++ii)                            \
      AF[ii] = *(const bf16x8*)(ab_ + offA[ii]);                                \
    _Pragma("unroll") for (int j = 0; j < 4; ++j)                               \
      BF[j] = *(const bf16x8*)(bb_ + offB[j]);                                  \
  } while (0)
#define MM(AF, BF)                                                              \
  do {                                                                          \
    __builtin_amdgcn_s_setprio(1);                                              \
    _Pragma("unroll") for (int ii = 0; ii < 8; ++ii)                            \
      _Pragma("unroll") for (int j = 0; j < 4; ++j)                             \
        acc[ii][j] = MFMA16(AF[ii], BF[j], acc[ii][j]);                         \
    __builtin_amdgcn_s_setprio(0);                                              \
  } while (0)

#define PHASE(I, CA, CB, NA, NB)                                                \
  do {                                                                          \
    int i_ = (I);                                                               \
    if (i_ + 1 < NP) RD(i_ + 1, NA, NB);                                        \
    if (i_ + 4 < NP) STG(i_ + 4);                                               \
    MM(CA, CB);                                                                 \
    if (i_ + 4 < NP)       { VMW(8); }                                          \
    else if (i_ + 4 == NP) { VMW(4); }                                          \
    else if (i_ + 3 == NP) { VMW(0); }                                          \
    LKW_BARR;                                                                   \
  } while (0)

  f32x4 acc[8][4] = {};
  int NP = K >> 5;                      // number of k-halves (K=5120 -> 160, even)

  bf16x8 afA[8], bfA[4], afB[8], bfB[4];

  // prologue: 4 groups in flight; complete G0,G1; read G0; guard slot0 WAR.
  STG(0); STG(1); STG(2); STG(3);
  VMW(8);
  __builtin_amdgcn_s_barrier();
  __builtin_amdgcn_sched_barrier(0);
  RD(0, afA, bfA);
  LKW_BARR;

  for (int i = 0; i < NP; i += 2) {
    PHASE(i,     afA, bfA, afB, bfB);
    PHASE(i + 1, afB, bfB, afA, bfA);
  }
#undef STG
#undef RD
#undef MM
#undef PHASE
#undef VMW
#undef LKW_BARR

#pragma unroll
  for (int i = 0; i < 8; ++i)
#pragma unroll
    for (int j = 0; j < 4; ++j) {
      long mrow = mBase + wm * 128 + i * 16 + g * 4;
      long ncol = nBase + wn * 64 + j * 16 + q;
      cstore(C + mrow * N + ncol, N, acc[i][j]);
    }
}

// ---------------- Kernel 4: split + head-RMSNorm + RoPE + gate (bf16 qkv) ----------------
__global__ __launch_bounds__(256) void split_kernel(
    const u16* __restrict__ qkv, const float* __restrict__ cosb,
    const float* __restrict__ sinb, const float* __restrict__ wq,
    const float* __restrict__ wk, u16* __restrict__ qb, u16* __restrict__ kb,
    float* __restrict__ gate) {
  int s = blockIdx.x;
  int w = threadIdx.x >> 6, l = threadIdx.x & 63;
  const u16* row = qkv + (size_t)s * QKV_P;
  float c0 = cosb[s * HD + l],      s0 = sinb[s * HD + l];
  float c1 = cosb[s * HD + 64 + l], s1 = sinb[s * HD + 64 + l];
  const float SCALE = 0.12751743f;  // (1/sqrt(128)) * log2(e)
  for (int h = w; h < NQh; h += 4) {
    float x0 = b2f(row[h * HD + l]), x1 = b2f(row[h * HD + 64 + l]);
    float ss = wave_sum64(x0 * x0 + x1 * x1);
    float n = rsqrtf(ss * (1.f / HD) + 1e-6f);
    x0 *= n * wq[l]; x1 *= n * wq[64 + l];
    qb[((size_t)s * NQh + h) * HD + l]      = f2bf((x0 * c0 - x1 * s0) * SCALE);
    qb[((size_t)s * NQh + h) * HD + 64 + l] = f2bf((x1 * c1 + x0 * s1) * SCALE);
  }
  for (int h = w; h < NKVh; h += 4) {
    float x0 = b2f(row[NQh * HD + h * HD + l]), x1 = b2f(row[NQh * HD + h * HD + 64 + l]);
    float ss = wave_sum64(x0 * x0 + x1 * x1);
    float n = rsqrtf(ss * (1.f / HD) + 1e-6f);
    x0 *= n * wk[l]; x1 *= n * wk[64 + l];
    kb[((size_t)h * S_LEN + s) * HD + l]      = f2bf(x0 * c0 - x1 * s0);
    kb[((size_t)h * S_LEN + s) * HD + 64 + l] = f2bf(x1 * c1 + x0 * s1);
  }
  if (threadIdx.x < NQh) {
    float gx = b2f(row[(NQh + 2 * NKVh) * HD + threadIdx.x]);
    gate[(size_t)s * NQh + threadIdx.x] = 1.f / (1.f + expf(-gx));
  }
}

// ---------------- Kernel 5: flash attention v8 (unchanged, passing) ----------------
__global__ __launch_bounds__(256) void attn_kernel(
    const u16* __restrict__ qb, const u16* __restrict__ kb,
    const u16* __restrict__ vT,
    u16* __restrict__ opart, float* __restrict__ lpart) {
  int L = blockIdx.x;                 // 0..1279
  int xcd = L & 7, t0 = L >> 3;       // t0: 0..159
  int G = xcd * 10 + (t0 >> 4);       // (head, z) group, 0..79
  int bx = t0 & 15;                   // s-chunk within group
  int h = G % NQh, z = G / NQh;
  int hk = h / 5;
  int w = threadIdx.x >> 6, l = threadIdx.x & 63;
  int g = l >> 4, q = l & 15;
  int s0 = bx * 128 + w * 32;
  int tid = threadIdx.x;

  __shared__ __align__(16) u16 Ks[2][32 * 128];     // 8KB x2 (swizzled content)
  __shared__ __align__(16) u16 Vs[2][128 * 32];     // 8KB x2 (swizzled content)
  __shared__ __align__(16) u16 Plds[4][2][16][40];  // per-wave private

  bf16x8 ones;
#pragma unroll
  for (int j = 0; j < 8; ++j) ones[j] = (short)0x3F80;  // bf16 1.0

  bf16x8 qf[2][4];
#pragma unroll
  for (int p = 0; p < 2; ++p)
#pragma unroll
    for (int kk = 0; kk < 4; ++kk)
      qf[p][kk] = *(const bf16x8*)(qb + ((size_t)(s0 + p * 16 + q) * NQh + h) * HD + kk * 32 + g * 8);

  const char* KhB = (const char*)(kb + ((size_t)hk * S_LEN + z * 1024) * HD);  // rows 256B
  const char* VhB = (const char*)(vT + (size_t)hk * HD * S_LEN + z * 1024);    // rows 4096B

  int Dk0 = tid * 16, Dk1 = 4096 + tid * 16;
  long ks0 = (long)(Dk0 >> 8) * 256 + ((Dk0 & 255) ^ (((Dk0 >> 8) & 7) << 4));
  long ks1 = (long)(Dk1 >> 8) * 256 + ((Dk1 & 255) ^ (((Dk1 >> 8) & 7) << 4));
  long vs0 = (long)(Dk0 >> 6) * 4096 + ((Dk0 & 63) ^ (((Dk0 >> 7) & 3) << 4));
  long vs1 = (long)(Dk1 >> 6) * 4096 + ((Dk1 & 63) ^ (((Dk1 >> 7) & 3) << 4));

#define STG(BUF, T_)                                                            \
  do {                                                                          \
    __builtin_amdgcn_global_load_lds((gas_ptr)(KhB + (long)(T_) * 8192 + ks0),  \
        (las_ptr)((char*)&Ks[BUF][0] + Dk0), 16, 0, 0);                         \
    __builtin_amdgcn_global_load_lds((gas_ptr)(KhB + (long)(T_) * 8192 + ks1),  \
        (las_ptr)((char*)&Ks[BUF][0] + Dk1), 16, 0, 0);                         \
    __builtin_amdgcn_global_load_lds((gas_ptr)(VhB + (long)(T_) * 64 + vs0),    \
        (las_ptr)((char*)&Vs[BUF][0] + Dk0), 16, 0, 0);                         \
    __builtin_amdgcn_global_load_lds((gas_ptr)(VhB + (long)(T_) * 64 + vs1),    \
        (las_ptr)((char*)&Vs[BUF][0] + Dk1), 16, 0, 0);                         \
  } while (0)

#define BARR                                                                    \
  do {                                                                          \
    __builtin_amdgcn_sched_barrier(0);                                          \
    __builtin_amdgcn_s_barrier();                                               \
    __builtin_amdgcn_sched_barrier(0);                                          \
  } while (0)

  f32x4 oacc[8][2] = {};
  f32x4 lacc[2] = {};
  int xq = (q & 7) << 4;              // K read swizzle (row = kt*16+q)
  int xv = ((q >> 1) & 3) << 4;       // V read swizzle (row = dt*16+q)

  STG(0, 0); STG(1, 1);
  __builtin_amdgcn_sched_barrier(0);
  asm volatile("s_waitcnt vmcnt(4)" ::: "memory");   // tile0 done
  BARR;

  for (int step = 0; step < 32; ++step) {
    const char* kc = (const char*)&Ks[step & 1][0];
    const char* vc = (const char*)&Vs[step & 1][0];

    f32x4 sacc[2][2] = {};
#pragma unroll
    for (int kk = 0; kk < 4; ++kk) {
#pragma unroll
      for (int kt = 0; kt < 2; ++kt) {
        bf16x8 kf = *(const bf16x8*)(kc + (kt * 16 + q) * 256 + ((kk * 64 + g * 16) ^ xq));
        sacc[kt][0] = MFMA16(kf, qf[0][kk], sacc[kt][0]);
        sacc[kt][1] = MFMA16(kf, qf[1][kk], sacc[kt][1]);
      }
    }
    bf16x8 va[8];
#pragma unroll
    for (int dt = 0; dt < 8; ++dt)
      va[dt] = *(const bf16x8*)(vc + (dt * 16 + q) * 64 + ((g * 16) ^ xv));

#pragma unroll
    for (int p = 0; p < 2; ++p) {
#pragma unroll
      for (int kt = 0; kt < 2; ++kt) {
        u16x4 pk;
#pragma unroll
        for (int r = 0; r < 4; ++r) pk[r] = f2bf_c(exp2f(sacc[kt][p][r]));
        *(u16x4*)&Plds[w][p][q][kt * 16 + g * 4] = pk;
      }
    }
    bf16x8 pf0 = *(const bf16x8*)&Plds[w][0][q][g * 8];
    bf16x8 pf1 = *(const bf16x8*)&Plds[w][1][q][g * 8];
    __builtin_amdgcn_s_setprio(1);
#pragma unroll
    for (int dt = 0; dt < 8; ++dt) {
      oacc[dt][0] = MFMA16(va[dt], pf0, oacc[dt][0]);
      oacc[dt][1] = MFMA16(va[dt], pf1, oacc[dt][1]);
    }
    lacc[0] = MFMA16(ones, pf0, lacc[0]);   // l += P . 1
    lacc[1] = MFMA16(ones, pf1, lacc[1]);
    __builtin_amdgcn_s_setprio(0);

    BARR;                               // all waves done reading buf(step)
    if (step + 2 < 32) {
      STG(step & 1, step + 2);
      __builtin_amdgcn_sched_barrier(0);
      asm volatile("s_waitcnt vmcnt(4)" ::: "memory");  // tile step+1 resident
      __builtin_amdgcn_sched_barrier(0);
    } else if (step + 1 < 32) {
      __builtin_amdgcn_sched_barrier(0);
      asm volatile("s_waitcnt vmcnt(0)" ::: "memory");
      __builtin_amdgcn_sched_barrier(0);
    }
    BARR;
  }
#undef STG
#undef BARR

#pragma unroll
  for (int p = 0; p < 2; ++p) {
    size_t row = (size_t)(s0 + p * 16 + q) * NQh + h;
    if (g == 0) lpart[(size_t)z * NROW + row] = lacc[p][0];
    u16* op = opart + ((size_t)z * NROW + row) * HD;
#pragma unroll
    for (int dt = 0; dt < 8; ++dt) {
      u16x4 o;
#pragma unroll
      for (int r = 0; r < 4; ++r) o[r] = f2bf_c(oacc[dt][p][r]);
      *(u16x4*)(op + dt * 16 + g * 4) = o;
    }
  }
}

// ---------------- Kernel 6: combine kv-split partials + gate ----------------
__global__ __launch_bounds__(256) void combine_kernel(
    const u16* __restrict__ opart, const float* __restrict__ lpart,
    const float* __restrict__ gate, u16* __restrict__ ob) {
  int t = blockIdx.x * 256 + threadIdx.x;
  int row = t >> 5, dv = (t & 31) * 4;
  float l0 = lpart[row], l1 = lpart[NROW + row];
  float sc = gate[row] / (l0 + l1);
  u16x4 o0 = *(const u16x4*)(opart + (size_t)row * HD + dv);
  u16x4 o1 = *(const u16x4*)(opart + (size_t)NROW * HD + (size_t)row * HD + dv);
  u16x4 o;
#pragma unroll
  for (int r = 0; r < 4; ++r) o[r] = f2bf(sc * (b2f(o0[r]) + b2f(o1[r])));
  *(u16x4*)(ob + (size_t)row * HD + dv) = o;
}

// ---------------- host ----------------
extern "C" void kernel_launch(void* const* d_in, const int* in_sizes, int n_in,
                              void* d_out, int out_size, void* d_ws, size_t ws_size,
                              hipStream_t stream) {
  const float* x     = (const float*)d_in[0];
  const float* rc    = (const float*)d_in[1];
  const float* rs    = (const float*)d_in[2];
  const float* wpre  = (const float*)d_in[3];
  const float* wqkv  = (const float*)d_in[4];
  const float* wqn   = (const float*)d_in[5];
  const float* wkn   = (const float*)d_in[6];
  const float* wproj = (const float*)d_in[7];
  float* out = (float*)d_out;

  char* ws = (char*)d_ws;
  size_t off = 0;
  auto alloc = [&](size_t bytes) -> void* {
    void* p = ws + off;
    off += (bytes + 255) & ~(size_t)255;
    return p;
  };
  u16*   xn     = (u16*)  alloc((size_t)S_LEN * HIDd * 2);        // dead after QKV GEMM
  u16*   wqkvT  = (u16*)  alloc((size_t)QKV_P * HIDd * 2);        // dead after QKV GEMM
  u16*   wprojT = (u16*)  alloc((size_t)HIDd * HIDd * 2);
  u16*   qkvb   = (u16*)  alloc((size_t)S_LEN * QKV_P * 2);       // bf16 qkv
  u16*   qb     = (u16*)  alloc((size_t)S_LEN * NQh * HD * 2);
  u16*   kb     = (u16*)  alloc((size_t)NKVh * S_LEN * HD * 2);
  u16*   vT     = (u16*)  alloc((size_t)NKVh * HD * S_LEN * 2);
  float* gate   = (float*)alloc((size_t)S_LEN * NQh * 4);
  u16*   ob     = (u16*)  alloc((size_t)S_LEN * NQh * HD * 2);
  if (off > ws_size) return;

  // attn partials overlap the dead xn+wqkvT region (~42.7MB < 97MB).
  u16*   opart = (u16*)ws;                                     // 2*NROW*HD bf16 = 42MB
  float* lpart = (float*)(opart + (size_t)2 * NROW * HD);      // 2*NROW f32

  prenorm_kernel<<<S_LEN, 256, 0, stream>>>(x, wpre, xn);
  transpose_cvt<<<dim3(QKV_P / 32, HIDd / 32, 1), 256, 0, stream>>>(
      wqkv, wqkvT, QKV_C, (long)QKV_C, (long)HIDd, 0, 0);
  transpose_cvt<<<dim3(HIDd / 32, HIDd / 32, 1), 256, 0, stream>>>(
      wproj, wprojT, HIDd, (long)HIDd, (long)HIDd, 0, 0);
  gemm8<u16><<<dim3(QKV_P / 256, S_LEN / 256), 512, 0, stream>>>(
      xn, wqkvT, qkvb, S_LEN, QKV_P, HIDd);
  split_kernel<<<S_LEN, 256, 0, stream>>>(qkvb, rc, rs, wqn, wkn, qb, kb, gate);
  transpose_bf16<<<dim3(HD / 32, S_LEN / 32, NKVh), 256, 0, stream>>>(
      qkvb + (NQh + NKVh) * HD, vT, (long)QKV_P, (long)S_LEN,
      128, (long)HD * S_LEN);
  attn_kernel<<<1280, 256, 0, stream>>>(qb, kb, vT, opart, lpart);
  combine_kernel<<<NROW * 32 / 256, 256, 0, stream>>>(
      opart, lpart, gate, ob);
  gemm8<float><<<dim3(HIDd / 256, S_LEN / 256), 512, 0, stream>>>(
      ob, wprojT, out, S_LEN, HIDd, HIDd);
}

// Round 18
// 552.527 us; speedup vs baseline: 6.1685x; 1.0331x over previous
//
#include <hip/hip_runtime.h>
#include <hip/hip_bf16.h>
#include <stdint.h>

#define S_LEN 2048
#define NQh   40
#define NKVh  8
#define HD    128
#define HIDd  5120
#define QKV_C 7208
#define QKV_P 7424   // padded to multiple of 256
#define NROW  (S_LEN * NQh)   // 81920 (q-row, head) pairs

typedef unsigned short u16;
typedef short bf16x8 __attribute__((ext_vector_type(8)));
typedef float f32x4  __attribute__((ext_vector_type(4)));
typedef u16   u16x4  __attribute__((ext_vector_type(4)));

typedef const __attribute__((address_space(1))) void* gas_ptr;
typedef __attribute__((address_space(3))) void*       las_ptr;

#define MFMA16(a, b, c) __builtin_amdgcn_mfma_f32_16x16x32_bf16(a, b, c, 0, 0, 0)

__device__ __forceinline__ u16 f2bf(float f) {
  union { float f; unsigned u; } v; v.f = f;
  return (u16)((v.u + 0x7fffu + ((v.u >> 16) & 1u)) >> 16);
}
__device__ __forceinline__ u16 f2bf_c(float f) {
  union { __hip_bfloat16 b; u16 u; } v;
  v.b = __float2bfloat16(f);
  return v.u;
}
__device__ __forceinline__ float b2f(u16 b) {
  union { unsigned u; float f; } v; v.u = ((unsigned)b) << 16; return v.f;
}

__device__ __forceinline__ float wave_sum64(float x) {
#pragma unroll
  for (int m = 32; m > 0; m >>= 1) x += __shfl_xor(x, m, 64);
  return x;
}

// C-store helpers (rows r at stride N, col fixed per lane)
__device__ __forceinline__ void cstore(float* cp, long strideN, const f32x4& v) {
#pragma unroll
  for (int r = 0; r < 4; ++r) cp[(long)r * strideN] = v[r];
}
__device__ __forceinline__ void cstore(u16* cp, long strideN, const f32x4& v) {
#pragma unroll
  for (int r = 0; r < 4; ++r) cp[(long)r * strideN] = f2bf_c(v[r]);
}

// ---------------- Kernel 1: pre-norm RMSNorm -> bf16 ----------------
__global__ __launch_bounds__(256) void prenorm_kernel(
    const float* __restrict__ x, const float* __restrict__ w, u16* __restrict__ xn) {
  int row = blockIdx.x;
  const float4* xr = (const float4*)(x + (size_t)row * HIDd);
  const float4* wr = (const float4*)w;
  float4 vx[5];
  float ss = 0.f;
#pragma unroll
  for (int c = 0; c < 5; ++c) {
    int i = c * 256 + threadIdx.x;
    vx[c] = xr[i];
    ss += vx[c].x * vx[c].x + vx[c].y * vx[c].y + vx[c].z * vx[c].z + vx[c].w * vx[c].w;
  }
  ss = wave_sum64(ss);
  __shared__ float red[4];
  if ((threadIdx.x & 63) == 0) red[threadIdx.x >> 6] = ss;
  __syncthreads();
  float tot = red[0] + red[1] + red[2] + red[3];
  float n = rsqrtf(tot * (1.f / HIDd) + 1e-6f);
  u16x4* out = (u16x4*)(xn + (size_t)row * HIDd);
#pragma unroll
  for (int c = 0; c < 5; ++c) {
    int i = c * 256 + threadIdx.x;
    float4 vw = wr[i];
    u16x4 o;
    o.x = f2bf(vx[c].x * n * vw.x);
    o.y = f2bf(vx[c].y * n * vw.y);
    o.z = f2bf(vx[c].z * n * vw.z);
    o.w = f2bf(vx[c].w * n * vw.w);
    out[i] = o;
  }
}

// ---------------- Kernel 2: transpose + fp32->bf16 (vectorized) ----------------
__global__ __launch_bounds__(256) void transpose_cvt(
    const float* __restrict__ src, u16* __restrict__ dst,
    int C, long ld_src, long ld_dst, long srcZ, long dstZ) {
  src += (long)blockIdx.z * srcZ;
  dst += (long)blockIdx.z * dstZ;
  __shared__ float t[32][34];
  int c0 = blockIdx.x * 32, r0 = blockIdx.y * 32;
  {
    int lc = threadIdx.x & 15, lr = threadIdx.x >> 4;
#pragma unroll
    for (int i = 0; i < 32; i += 16) {
      int r = r0 + lr + i;
      int c = c0 + lc * 2;
      float2 v = make_float2(0.f, 0.f);
      if (c < C) v = *(const float2*)(src + (long)r * ld_src + c);
      *(float2*)&t[lr + i][lc * 2] = v;
    }
  }
  __syncthreads();
  {
    int cc = threadIdx.x >> 3;
    int rq = (threadIdx.x & 7) * 4;
    int c = c0 + cc;
    if (c < C) {
      u16x4 o;
#pragma unroll
      for (int rr = 0; rr < 4; ++rr) o[rr] = f2bf(t[rq + rr][cc]);
      *(u16x4*)(dst + (long)c * ld_dst + (r0 + rq)) = o;
    }
  }
}

// ---------------- Kernel 2b: bf16 -> bf16 transpose (for V extraction) ----------------
__global__ __launch_bounds__(256) void transpose_bf16(
    const u16* __restrict__ src, u16* __restrict__ dst,
    long ld_src, long ld_dst, long srcZ, long dstZ) {
  src += (long)blockIdx.z * srcZ;
  dst += (long)blockIdx.z * dstZ;
  __shared__ u16 t[32][34];
  int c0 = blockIdx.x * 32, r0 = blockIdx.y * 32;
  {
    int lc = threadIdx.x & 15, lr = threadIdx.x >> 4;
#pragma unroll
    for (int i = 0; i < 32; i += 16)
      *(unsigned*)&t[lr + i][lc * 2] =
          *(const unsigned*)(src + (long)(r0 + lr + i) * ld_src + c0 + lc * 2);
  }
  __syncthreads();
  {
    int cc = threadIdx.x >> 3;
    int rq = (threadIdx.x & 7) * 4;
    u16x4 o;
#pragma unroll
    for (int rr = 0; rr < 4; ++rr) o[rr] = t[rq + rr][cc];
    *(u16x4*)(dst + (long)(c0 + cc) * ld_dst + (r0 + rq)) = o;
  }
}

// ---------------- Kernel 3: 256x256 GEMM, register-pipelined k-half ring ----------------
// (round-15 verified: 175-177 us/dispatch, VGPR 124 arch + 128 acc, 0 conflicts)
template<typename OutT>
__global__ __launch_bounds__(512, 1) void gemm8(
    const u16* __restrict__ A, const u16* __restrict__ BT, OutT* __restrict__ C,
    int M, int N, int K) {
  __shared__ __align__(16) char AL[4 * 16384];
  __shared__ __align__(16) char BL[4 * 16384];

  int tid = threadIdx.x, w = tid >> 6, l = tid & 63;
  int wm = w >> 2, wn = w & 3;
  int g = l >> 4, q = l & 15;

  int nwg = gridDim.x * gridDim.y;
  int wgid = blockIdx.y * gridDim.x + blockIdx.x;
  int cpx = nwg >> 3;
  int swz = (wgid & 7) * cpx + (wgid >> 3);
  int bx = swz % gridDim.x, by = swz / gridDim.x;
  long mBase = (long)by * 256, nBase = (long)bx * 256;
  long Kb = (long)K * 2;
  const char* Ag = (const char*)A + mBase * Kb;
  const char* Bg = (const char*)BT + nBase * Kb;

  int d0 = tid * 16, d1 = 8192 + tid * 16;
  long soff0 = (long)(d0 >> 6) * Kb + ((d0 & 63) ^ (((d0 >> 7) & 3) << 4));
  long soff1 = (long)(d1 >> 6) * Kb + ((d1 & 63) ^ (((d1 >> 7) & 3) << 4));

#define STG(J)                                                                  \
  do {                                                                          \
    long kb_ = (long)(J) * 64;                                                  \
    char* la_ = AL + ((J) & 3) * 16384;                                         \
    char* lb_ = BL + ((J) & 3) * 16384;                                         \
    __builtin_amdgcn_global_load_lds((gas_ptr)(Ag + soff0 + kb_),               \
        (las_ptr)(la_ + d0), 16, 0, 0);                                         \
    __builtin_amdgcn_global_load_lds((gas_ptr)(Ag + soff1 + kb_),               \
        (las_ptr)(la_ + d1), 16, 0, 0);                                         \
    __builtin_amdgcn_global_load_lds((gas_ptr)(Bg + soff0 + kb_),               \
        (las_ptr)(lb_ + d0), 16, 0, 0);                                         \
    __builtin_amdgcn_global_load_lds((gas_ptr)(Bg + soff1 + kb_),               \
        (las_ptr)(lb_ + d1), 16, 0, 0);                                         \
  } while (0)

#define VMW(NLIT)                                                               \
  do {                                                                          \
    asm volatile("s_waitcnt vmcnt(" #NLIT ")" ::: "memory");                    \
    __builtin_amdgcn_sched_barrier(0);                                          \
  } while (0)
#define LKW_BARR                                                                \
  do {                                                                          \
    asm volatile("s_waitcnt lgkmcnt(0)" ::: "memory");                          \
    __builtin_amdgcn_sched_barrier(0);                                          \
    __builtin_amdgcn_s_barrier();                                               \
    __builtin_amdgcn_sched_barrier(0);                                          \
  } while (0)

  int offA[8], offB[4];
#pragma unroll
  for (int i = 0; i < 8; ++i) {
    int r = wm * 128 + i * 16 + q;
    offA[i] = r * 64 + ((g * 16) ^ (((r >> 1) & 3) << 4));
  }
#pragma unroll
  for (int j = 0; j < 4; ++j) {
    int r = wn * 64 + j * 16 + q;
    offB[j] = r * 64 + ((g * 16) ^ (((r >> 1) & 3) << 4));
  }

#define RD(J, AF, BF)                                                           \
  do {                                                                          \
    const char* ab_ = AL + ((J) & 3) * 16384;                                   \
    const char* bb_ = BL + ((J) & 3) * 16384;                                   \
    _Pragma("unroll") for (int ii = 0; ii < 8; ++ii)                            \
      AF[ii] = *(const bf16x8*)(ab_ + offA[ii]);                                \
    _Pragma("unroll") for (int j = 0; j < 4; ++j)                               \
      BF[j] = *(const bf16x8*)(bb_ + offB[j]);                                  \
  } while (0)
#define MM(AF, BF)                                                              \
  do {                                                                          \
    __builtin_amdgcn_s_setprio(1);                                              \
    _Pragma("unroll") for (int ii = 0; ii < 8; ++ii)                            \
      _Pragma("unroll") for (int j = 0; j < 4; ++j)                             \
        acc[ii][j] = MFMA16(AF[ii], BF[j], acc[ii][j]);                         \
    __builtin_amdgcn_s_setprio(0);                                              \
  } while (0)

#define PHASE(I, CA, CB, NA, NB)                                                \
  do {                                                                          \
    int i_ = (I);                                                               \
    if (i_ + 1 < NP) RD(i_ + 1, NA, NB);                                        \
    if (i_ + 4 < NP) STG(i_ + 4);                                               \
    MM(CA, CB);                                                                 \
    if (i_ + 4 < NP)       { VMW(8); }                                          \
    else if (i_ + 4 == NP) { VMW(4); }                                          \
    else if (i_ + 3 == NP) { VMW(0); }                                          \
    LKW_BARR;                                                                   \
  } while (0)

  f32x4 acc[8][4] = {};
  int NP = K >> 5;                      // number of k-halves (K=5120 -> 160, even)

  bf16x8 afA[8], bfA[4], afB[8], bfB[4];

  STG(0); STG(1); STG(2); STG(3);
  VMW(8);
  __builtin_amdgcn_s_barrier();
  __builtin_amdgcn_sched_barrier(0);
  RD(0, afA, bfA);
  LKW_BARR;

  for (int i = 0; i < NP; i += 2) {
    PHASE(i,     afA, bfA, afB, bfB);
    PHASE(i + 1, afB, bfB, afA, bfA);
  }
#undef STG
#undef RD
#undef MM
#undef PHASE
#undef VMW
#undef LKW_BARR

#pragma unroll
  for (int i = 0; i < 8; ++i)
#pragma unroll
    for (int j = 0; j < 4; ++j) {
      long mrow = mBase + wm * 128 + i * 16 + g * 4;
      long ncol = nBase + wn * 64 + j * 16 + q;
      cstore(C + mrow * N + ncol, N, acc[i][j]);
    }
}

// ---------------- Kernel 3b: 128x256 GEMM, 2-slot dbuf, 3 blocks/CU ----------------
// For the fill-limited proj (grid 20x16=320 blocks). 8 waves (2M x 4N), wave
// tile 64x64 -> acc 64 AGPR; arch ~90 VGPR -> ~155 total -> 3 waves/SIMD, and
// LDS 48 KiB -> 3 blocks/CU co-resident: the per-phase vmcnt(0) drain hides
// under the other blocks' waves (m114 mechanism; r16-validated structure, the
// reg-cap that killed r16 is absent because acc is half).
// Per phase: RD(i) -> STG(i+1, other slot) -> 16 MFMA -> vmcnt(0)+lgkmcnt(0)
// -> barrier. Row-local XOR swizzle identical to gemm8.
template<typename OutT>
__global__ __launch_bounds__(512, 1) void gemm_dbuf(
    const u16* __restrict__ A, const u16* __restrict__ BT, OutT* __restrict__ C,
    int M, int N, int K) {
  __shared__ __align__(16) char AL[2 * 8192];    // 128 rows x 32k x 2B per slot
  __shared__ __align__(16) char BL[2 * 16384];   // 256 rows x 32k x 2B per slot

  int tid = threadIdx.x, w = tid >> 6, l = tid & 63;
  int wm = w >> 2, wn = w & 3;
  int g = l >> 4, q = l & 15;

  int nwg = gridDim.x * gridDim.y;
  int wgid = blockIdx.y * gridDim.x + blockIdx.x;
  int cpx = nwg >> 3;
  int swz = (wgid & 7) * cpx + (wgid >> 3);
  int bx = swz % gridDim.x, by = swz / gridDim.x;
  long mBase = (long)by * 128, nBase = (long)bx * 256;
  long Kb = (long)K * 2;
  const char* Ag = (const char*)A + mBase * Kb;
  const char* Bg = (const char*)BT + nBase * Kb;

  // staging: A = 8192 B/slot -> 1 load/thread; B = 16384 B/slot -> 2 loads.
  int dA = tid * 16;                       // 0..8191
  int dB0 = tid * 16, dB1 = 8192 + tid * 16;
  long sA  = (long)(dA  >> 6) * Kb + ((dA  & 63) ^ (((dA  >> 7) & 3) << 4));
  long sB0 = (long)(dB0 >> 6) * Kb + ((dB0 & 63) ^ (((dB0 >> 7) & 3) << 4));
  long sB1 = (long)(dB1 >> 6) * Kb + ((dB1 & 63) ^ (((dB1 >> 7) & 3) << 4));

#define STG(J)                                                                  \
  do {                                                                          \
    long kb_ = (long)(J) * 64;                                                  \
    char* la_ = AL + ((J) & 1) * 8192;                                          \
    char* lb_ = BL + ((J) & 1) * 16384;                                         \
    __builtin_amdgcn_global_load_lds((gas_ptr)(Ag + sA + kb_),                  \
        (las_ptr)(la_ + dA), 16, 0, 0);                                         \
    __builtin_amdgcn_global_load_lds((gas_ptr)(Bg + sB0 + kb_),                 \
        (las_ptr)(lb_ + dB0), 16, 0, 0);                                        \
    __builtin_amdgcn_global_load_lds((gas_ptr)(Bg + sB1 + kb_),                 \
        (las_ptr)(lb_ + dB1), 16, 0, 0);                                        \
  } while (0)

#define DRAIN_BARR                                                              \
  do {                                                                          \
    asm volatile("s_waitcnt vmcnt(0) lgkmcnt(0)" ::: "memory");                 \
    __builtin_amdgcn_sched_barrier(0);                                          \
    __builtin_amdgcn_s_barrier();                                               \
    __builtin_amdgcn_sched_barrier(0);                                          \
  } while (0)

  int offA[4], offB[4];
#pragma unroll
  for (int i = 0; i < 4; ++i) {
    int r = wm * 64 + i * 16 + q;
    offA[i] = r * 64 + ((g * 16) ^ (((r >> 1) & 3) << 4));
  }
#pragma unroll
  for (int j = 0; j < 4; ++j) {
    int r = wn * 64 + j * 16 + q;
    offB[j] = r * 64 + ((g * 16) ^ (((r >> 1) & 3) << 4));
  }

  f32x4 acc[4][4] = {};
  int NP = K >> 5;
  bf16x8 af[4], bf[4];

  STG(0);
  DRAIN_BARR;

  for (int i = 0; i < NP; ++i) {
    const char* ab = AL + (i & 1) * 8192;
    const char* bb = BL + (i & 1) * 16384;
#pragma unroll
    for (int ii = 0; ii < 4; ++ii) af[ii] = *(const bf16x8*)(ab + offA[ii]);
#pragma unroll
    for (int j = 0; j < 4; ++j)    bf[j]  = *(const bf16x8*)(bb + offB[j]);
    if (i + 1 < NP) STG(i + 1);
    __builtin_amdgcn_s_setprio(1);
#pragma unroll
    for (int ii = 0; ii < 4; ++ii)
#pragma unroll
      for (int j = 0; j < 4; ++j)
        acc[ii][j] = MFMA16(af[ii], bf[j], acc[ii][j]);
    __builtin_amdgcn_s_setprio(0);
    DRAIN_BARR;
  }
#undef STG
#undef DRAIN_BARR

#pragma unroll
  for (int i = 0; i < 4; ++i)
#pragma unroll
    for (int j = 0; j < 4; ++j) {
      long mrow = mBase + wm * 64 + i * 16 + g * 4;
      long ncol = nBase + wn * 64 + j * 16 + q;
      cstore(C + mrow * N + ncol, N, acc[i][j]);
    }
}

// ---------------- Kernel 4: split + head-RMSNorm + RoPE + gate (bf16 qkv) ----------------
__global__ __launch_bounds__(256) void split_kernel(
    const u16* __restrict__ qkv, const float* __restrict__ cosb,
    const float* __restrict__ sinb, const float* __restrict__ wq,
    const float* __restrict__ wk, u16* __restrict__ qb, u16* __restrict__ kb,
    float* __restrict__ gate) {
  int s = blockIdx.x;
  int w = threadIdx.x >> 6, l = threadIdx.x & 63;
  const u16* row = qkv + (size_t)s * QKV_P;
  float c0 = cosb[s * HD + l],      s0 = sinb[s * HD + l];
  float c1 = cosb[s * HD + 64 + l], s1 = sinb[s * HD + 64 + l];
  const float SCALE = 0.12751743f;  // (1/sqrt(128)) * log2(e)
  for (int h = w; h < NQh; h += 4) {
    float x0 = b2f(row[h * HD + l]), x1 = b2f(row[h * HD + 64 + l]);
    float ss = wave_sum64(x0 * x0 + x1 * x1);
    float n = rsqrtf(ss * (1.f / HD) + 1e-6f);
    x0 *= n * wq[l]; x1 *= n * wq[64 + l];
    qb[((size_t)s * NQh + h) * HD + l]      = f2bf((x0 * c0 - x1 * s0) * SCALE);
    qb[((size_t)s * NQh + h) * HD + 64 + l] = f2bf((x1 * c1 + x0 * s1) * SCALE);
  }
  for (int h = w; h < NKVh; h += 4) {
    float x0 = b2f(row[NQh * HD + h * HD + l]), x1 = b2f(row[NQh * HD + h * HD + 64 + l]);
    float ss = wave_sum64(x0 * x0 + x1 * x1);
    float n = rsqrtf(ss * (1.f / HD) + 1e-6f);
    x0 *= n * wk[l]; x1 *= n * wk[64 + l];
    kb[((size_t)h * S_LEN + s) * HD + l]      = f2bf(x0 * c0 - x1 * s0);
    kb[((size_t)h * S_LEN + s) * HD + 64 + l] = f2bf(x1 * c1 + x0 * s1);
  }
  if (threadIdx.x < NQh) {
    float gx = b2f(row[(NQh + 2 * NKVh) * HD + threadIdx.x]);
    gate[(size_t)s * NQh + threadIdx.x] = 1.f / (1.f + expf(-gx));
  }
}

// ---------------- Kernel 5: flash attention v8 (unchanged, passing) ----------------
__global__ __launch_bounds__(256) void attn_kernel(
    const u16* __restrict__ qb, const u16* __restrict__ kb,
    const u16* __restrict__ vT,
    u16* __restrict__ opart, float* __restrict__ lpart) {
  int L = blockIdx.x;                 // 0..1279
  int xcd = L & 7, t0 = L >> 3;       // t0: 0..159
  int G = xcd * 10 + (t0 >> 4);       // (head, z) group, 0..79
  int bx = t0 & 15;                   // s-chunk within group
  int h = G % NQh, z = G / NQh;
  int hk = h / 5;
  int w = threadIdx.x >> 6, l = threadIdx.x & 63;
  int g = l >> 4, q = l & 15;
  int s0 = bx * 128 + w * 32;
  int tid = threadIdx.x;

  __shared__ __align__(16) u16 Ks[2][32 * 128];     // 8KB x2 (swizzled content)
  __shared__ __align__(16) u16 Vs[2][128 * 32];     // 8KB x2 (swizzled content)
  __shared__ __align__(16) u16 Plds[4][2][16][40];  // per-wave private

  bf16x8 ones;
#pragma unroll
  for (int j = 0; j < 8; ++j) ones[j] = (short)0x3F80;  // bf16 1.0

  bf16x8 qf[2][4];
#pragma unroll
  for (int p = 0; p < 2; ++p)
#pragma unroll
    for (int kk = 0; kk < 4; ++kk)
      qf[p][kk] = *(const bf16x8*)(qb + ((size_t)(s0 + p * 16 + q) * NQh + h) * HD + kk * 32 + g * 8);

  const char* KhB = (const char*)(kb + ((size_t)hk * S_LEN + z * 1024) * HD);  // rows 256B
  const char* VhB = (const char*)(vT + (size_t)hk * HD * S_LEN + z * 1024);    // rows 4096B

  int Dk0 = tid * 16, Dk1 = 4096 + tid * 16;
  long ks0 = (long)(Dk0 >> 8) * 256 + ((Dk0 & 255) ^ (((Dk0 >> 8) & 7) << 4));
  long ks1 = (long)(Dk1 >> 8) * 256 + ((Dk1 & 255) ^ (((Dk1 >> 8) & 7) << 4));
  long vs0 = (long)(Dk0 >> 6) * 4096 + ((Dk0 & 63) ^ (((Dk0 >> 7) & 3) << 4));
  long vs1 = (long)(Dk1 >> 6) * 4096 + ((Dk1 & 63) ^ (((Dk1 >> 7) & 3) << 4));

#define STG(BUF, T_)                                                            \
  do {                                                                          \
    __builtin_amdgcn_global_load_lds((gas_ptr)(KhB + (long)(T_) * 8192 + ks0),  \
        (las_ptr)((char*)&Ks[BUF][0] + Dk0), 16, 0, 0);                         \
    __builtin_amdgcn_global_load_lds((gas_ptr)(KhB + (long)(T_) * 8192 + ks1),  \
        (las_ptr)((char*)&Ks[BUF][0] + Dk1), 16, 0, 0);                         \
    __builtin_amdgcn_global_load_lds((gas_ptr)(VhB + (long)(T_) * 64 + vs0),    \
        (las_ptr)((char*)&Vs[BUF][0] + Dk0), 16, 0, 0);                         \
    __builtin_amdgcn_global_load_lds((gas_ptr)(VhB + (long)(T_) * 64 + vs1),    \
        (las_ptr)((char*)&Vs[BUF][0] + Dk1), 16, 0, 0);                         \
  } while (0)

#define BARR                                                                    \
  do {                                                                          \
    __builtin_amdgcn_sched_barrier(0);                                          \
    __builtin_amdgcn_s_barrier();                                               \
    __builtin_amdgcn_sched_barrier(0);                                          \
  } while (0)

  f32x4 oacc[8][2] = {};
  f32x4 lacc[2] = {};
  int xq = (q & 7) << 4;              // K read swizzle (row = kt*16+q)
  int xv = ((q >> 1) & 3) << 4;       // V read swizzle (row = dt*16+q)

  STG(0, 0); STG(1, 1);
  __builtin_amdgcn_sched_barrier(0);
  asm volatile("s_waitcnt vmcnt(4)" ::: "memory");   // tile0 done
  BARR;

  for (int step = 0; step < 32; ++step) {
    const char* kc = (const char*)&Ks[step & 1][0];
    const char* vc = (const char*)&Vs[step & 1][0];

    f32x4 sacc[2][2] = {};
#pragma unroll
    for (int kk = 0; kk < 4; ++kk) {
#pragma unroll
      for (int kt = 0; kt < 2; ++kt) {
        bf16x8 kf = *(const bf16x8*)(kc + (kt * 16 + q) * 256 + ((kk * 64 + g * 16) ^ xq));
        sacc[kt][0] = MFMA16(kf, qf[0][kk], sacc[kt][0]);
        sacc[kt][1] = MFMA16(kf, qf[1][kk], sacc[kt][1]);
      }
    }
    bf16x8 va[8];
#pragma unroll
    for (int dt = 0; dt < 8; ++dt)
      va[dt] = *(const bf16x8*)(vc + (dt * 16 + q) * 64 + ((g * 16) ^ xv));

#pragma unroll
    for (int p = 0; p < 2; ++p) {
#pragma unroll
      for (int kt = 0; kt < 2; ++kt) {
        u16x4 pk;
#pragma unroll
        for (int r = 0; r < 4; ++r) pk[r] = f2bf_c(exp2f(sacc[kt][p][r]));
        *(u16x4*)&Plds[w][p][q][kt * 16 + g * 4] = pk;
      }
    }
    bf16x8 pf0 = *(const bf16x8*)&Plds[w][0][q][g * 8];
    bf16x8 pf1 = *(const bf16x8*)&Plds[w][1][q][g * 8];
    __builtin_amdgcn_s_setprio(1);
#pragma unroll
    for (int dt = 0; dt < 8; ++dt) {
      oacc[dt][0] = MFMA16(va[dt], pf0, oacc[dt][0]);
      oacc[dt][1] = MFMA16(va[dt], pf1, oacc[dt][1]);
    }
    lacc[0] = MFMA16(ones, pf0, lacc[0]);   // l += P . 1
    lacc[1] = MFMA16(ones, pf1, lacc[1]);
    __builtin_amdgcn_s_setprio(0);

    BARR;                               // all waves done reading buf(step)
    if (step + 2 < 32) {
      STG(step & 1, step + 2);
      __builtin_amdgcn_sched_barrier(0);
      asm volatile("s_waitcnt vmcnt(4)" ::: "memory");  // tile step+1 resident
      __builtin_amdgcn_sched_barrier(0);
    } else if (step + 1 < 32) {
      __builtin_amdgcn_sched_barrier(0);
      asm volatile("s_waitcnt vmcnt(0)" ::: "memory");
      __builtin_amdgcn_sched_barrier(0);
    }
    BARR;
  }
#undef STG
#undef BARR

#pragma unroll
  for (int p = 0; p < 2; ++p) {
    size_t row = (size_t)(s0 + p * 16 + q) * NQh + h;
    if (g == 0) lpart[(size_t)z * NROW + row] = lacc[p][0];
    u16* op = opart + ((size_t)z * NROW + row) * HD;
#pragma unroll
    for (int dt = 0; dt < 8; ++dt) {
      u16x4 o;
#pragma unroll
      for (int r = 0; r < 4; ++r) o[r] = f2bf_c(oacc[dt][p][r]);
      *(u16x4*)(op + dt * 16 + g * 4) = o;
    }
  }
}

// ---------------- Kernel 6: combine kv-split partials + gate ----------------
__global__ __launch_bounds__(256) void combine_kernel(
    const u16* __restrict__ opart, const float* __restrict__ lpart,
    const float* __restrict__ gate, u16* __restrict__ ob) {
  int t = blockIdx.x * 256 + threadIdx.x;
  int row = t >> 5, dv = (t & 31) * 4;
  float l0 = lpart[row], l1 = lpart[NROW + row];
  float sc = gate[row] / (l0 + l1);
  u16x4 o0 = *(const u16x4*)(opart + (size_t)row * HD + dv);
  u16x4 o1 = *(const u16x4*)(opart + (size_t)NROW * HD + (size_t)row * HD + dv);
  u16x4 o;
#pragma unroll
  for (int r = 0; r < 4; ++r) o[r] = f2bf(sc * (b2f(o0[r]) + b2f(o1[r])));
  *(u16x4*)(ob + (size_t)row * HD + dv) = o;
}

// ---------------- host ----------------
extern "C" void kernel_launch(void* const* d_in, const int* in_sizes, int n_in,
                              void* d_out, int out_size, void* d_ws, size_t ws_size,
                              hipStream_t stream) {
  const float* x     = (const float*)d_in[0];
  const float* rc    = (const float*)d_in[1];
  const float* rs    = (const float*)d_in[2];
  const float* wpre  = (const float*)d_in[3];
  const float* wqkv  = (const float*)d_in[4];
  const float* wqn   = (const float*)d_in[5];
  const float* wkn   = (const float*)d_in[6];
  const float* wproj = (const float*)d_in[7];
  float* out = (float*)d_out;

  char* ws = (char*)d_ws;
  size_t off = 0;
  auto alloc = [&](size_t bytes) -> void* {
    void* p = ws + off;
    off += (bytes + 255) & ~(size_t)255;
    return p;
  };
  u16*   xn     = (u16*)  alloc((size_t)S_LEN * HIDd * 2);        // dead after QKV GEMM
  u16*   wqkvT  = (u16*)  alloc((size_t)QKV_P * HIDd * 2);        // dead after QKV GEMM
  u16*   wprojT = (u16*)  alloc((size_t)HIDd * HIDd * 2);
  u16*   qkvb   = (u16*)  alloc((size_t)S_LEN * QKV_P * 2);       // bf16 qkv
  u16*   qb     = (u16*)  alloc((size_t)S_LEN * NQh * HD * 2);
  u16*   kb     = (u16*)  alloc((size_t)NKVh * S_LEN * HD * 2);
  u16*   vT     = (u16*)  alloc((size_t)NKVh * HD * S_LEN * 2);
  float* gate   = (float*)alloc((size_t)S_LEN * NQh * 4);
  u16*   ob     = (u16*)  alloc((size_t)S_LEN * NQh * HD * 2);
  if (off > ws_size) return;

  // attn partials overlap the dead xn+wqkvT region (~42.7MB < 97MB).
  u16*   opart = (u16*)ws;                                     // 2*NROW*HD bf16 = 42MB
  float* lpart = (float*)(opart + (size_t)2 * NROW * HD);      // 2*NROW f32

  prenorm_kernel<<<S_LEN, 256, 0, stream>>>(x, wpre, xn);
  transpose_cvt<<<dim3(QKV_P / 32, HIDd / 32, 1), 256, 0, stream>>>(
      wqkv, wqkvT, QKV_C, (long)QKV_C, (long)HIDd, 0, 0);
  transpose_cvt<<<dim3(HIDd / 32, HIDd / 32, 1), 256, 0, stream>>>(
      wproj, wprojT, HIDd, (long)HIDd, (long)HIDd, 0, 0);
  gemm8<u16><<<dim3(QKV_P / 256, S_LEN / 256), 512, 0, stream>>>(
      xn, wqkvT, qkvb, S_LEN, QKV_P, HIDd);
  split_kernel<<<S_LEN, 256, 0, stream>>>(qkvb, rc, rs, wqn, wkn, qb, kb, gate);
  transpose_bf16<<<dim3(HD / 32, S_LEN / 32, NKVh), 256, 0, stream>>>(
      qkvb + (NQh + NKVh) * HD, vT, (long)QKV_P, (long)S_LEN,
      128, (long)HD * S_LEN);
  attn_kernel<<<1280, 256, 0, stream>>>(qb, kb, vT, opart, lpart);
  combine_kernel<<<NROW * 32 / 256, 256, 0, stream>>>(
      opart, lpart, gate, ob);
  gemm_dbuf<float><<<dim3(HIDd / 256, S_LEN / 128), 512, 0, stream>>>(
      ob, wprojT, out, S_LEN, HIDd, HIDd);
}